// Round 1
// baseline (1244.395 us; speedup 1.0000x reference)
//
#include <hip/hip_runtime.h>
#include <hip/hip_bf16.h>

// Problem constants (from reference): B=8, TS=32, L=1025, D=512, WIN=2
// m has M = 8*32*513 = 131328 rows of F = 1024 features.
#define L_SEQ 1025
#define D_MODEL 512
#define KDIM 1024
#define NDIM 512
#define BM 32
#define M_ROWS 131328

typedef __bf16 bf16x4 __attribute__((ext_vector_type(4)));
typedef __bf16 bf16x8 __attribute__((ext_vector_type(8)));
typedef float f32x4 __attribute__((ext_vector_type(4)));

// lin_w is [K=1024][N=512] fp32 -> Bt bf16 [N=512][K=1024] (n-major) in ws
__global__ void prep_b_kernel(const float* __restrict__ lin_w,
                              __bf16* __restrict__ Bt) {
    int t = blockIdx.x * 256 + threadIdx.x;   // 0 .. 524287
    int n = t >> 10;
    int k = t & 1023;
    Bt[t] = (__bf16)lin_w[k * NDIM + n];
}

__global__ __launch_bounds__(256, 2)
void fused_ln_gemm_kernel(const float* __restrict__ x,
                          const float* __restrict__ norm_w,
                          const float* __restrict__ norm_b,
                          const __bf16* __restrict__ Bt,
                          const float* __restrict__ lin_b,
                          float* __restrict__ out) {
    // A tile in LDS, bf16, layout [kc=k/8][m][j=k%8] with XOR swizzle on m:
    // idx(kc,m,j) = (kc*32 + (m ^ (kc&31)))*8 + j   -- 64 KiB exactly.
    __shared__ __bf16 Alds[BM * KDIM];

    const int t = threadIdx.x;
    const int g0 = blockIdx.x * BM;

    // ---------------- Phase 1: gather + LayerNorm -> LDS (bf16) -------------
    {
        const int c = t & 31;        // 32 threads per row
        const int rsub = t >> 5;     // 8 rows at a time
        const int kbase = c * 4;
        #pragma unroll
        for (int iter = 0; iter < 4; ++iter) {
            const int r = iter * 8 + rsub;
            const int g = g0 + r;
            const int b_ts = g / 513;
            const int s = g - b_ts * 513;
            const float* xb = x + (size_t)b_ts * (L_SEQ * D_MODEL);
            const int l0 = s ? (2 * s - 1) : 0;
            const int l1 = s ? (2 * s) : 0;
            const float* p0 = xb + (size_t)l0 * D_MODEL;
            const float* p1 = xb + (size_t)l1 * D_MODEL;

            f32x4 v[8];
            float sum = 0.f, sumsq = 0.f;
            #pragma unroll
            for (int i = 0; i < 8; ++i) {
                int k = kbase + i * 128;
                const float* p = (i < 4) ? (p0 + k) : (p1 + (k - D_MODEL));
                v[i] = *(const f32x4*)p;
                sum += v[i][0] + v[i][1] + v[i][2] + v[i][3];
                sumsq += v[i][0] * v[i][0] + v[i][1] * v[i][1]
                       + v[i][2] * v[i][2] + v[i][3] * v[i][3];
            }
            // reduce across the 32 threads of this row (within wave halves)
            #pragma unroll
            for (int off = 16; off >= 1; off >>= 1) {
                sum += __shfl_xor(sum, off);
                sumsq += __shfl_xor(sumsq, off);
            }
            const float mu = sum * (1.f / 1024.f);
            const float var = sumsq * (1.f / 1024.f) - mu * mu;
            const float rs = rsqrtf(var + 1e-5f);

            #pragma unroll
            for (int i = 0; i < 8; ++i) {
                int k = kbase + i * 128;
                f32x4 w4 = *(const f32x4*)(norm_w + k);
                f32x4 b4 = *(const f32x4*)(norm_b + k);
                bf16x4 o;
                #pragma unroll
                for (int q = 0; q < 4; ++q)
                    o[q] = (__bf16)((v[i][q] - mu) * rs * w4[q] + b4[q]);
                const int kc = k >> 3;
                const int j = k & 7;            // 0 or 4
                const int row = r ^ (kc & 31);  // swizzle
                *(bf16x4*)&Alds[(kc * 32 + row) * 8 + j] = o;
            }
        }
    }
    __syncthreads();

    // ---------------- Phase 2: bf16 MFMA GEMM (32 x 512 per block) ----------
    const int lane = t & 63;
    const int wave = t >> 6;
    const int col = lane & 15;
    const int quad = lane >> 4;
    const int n0 = wave * 128;

    f32x4 acc[2][8] = {};
    const __bf16* bbase = Bt + (size_t)(n0 + col) * KDIM + quad * 8;

    #pragma unroll 4
    for (int ks = 0; ks < KDIM; ks += 32) {
        const int kc = (ks >> 3) + quad;
        const int rot = kc & 31;
        bf16x8 a0 = *(const bf16x8*)&Alds[(kc * 32 + (col ^ rot)) * 8];
        bf16x8 a1 = *(const bf16x8*)&Alds[(kc * 32 + ((16 + col) ^ rot)) * 8];
        #pragma unroll
        for (int nt = 0; nt < 8; ++nt) {
            bf16x8 b = *(const bf16x8*)(bbase + nt * (16 * KDIM) + ks);
            acc[0][nt] = __builtin_amdgcn_mfma_f32_16x16x32_bf16(a0, b, acc[0][nt], 0, 0, 0);
            acc[1][nt] = __builtin_amdgcn_mfma_f32_16x16x32_bf16(a1, b, acc[1][nt], 0, 0, 0);
        }
    }

    // ---------------- Epilogue: + lin_b, store fp32 -------------------------
    #pragma unroll
    for (int nt = 0; nt < 8; ++nt) {
        const int n = n0 + nt * 16 + col;
        const float bias = lin_b[n];
        #pragma unroll
        for (int mt = 0; mt < 2; ++mt) {
            const int row = g0 + mt * 16 + quad * 4;
            #pragma unroll
            for (int rg = 0; rg < 4; ++rg) {
                out[(size_t)(row + rg) * NDIM + n] = acc[mt][nt][rg] + bias;
            }
        }
    }
}

extern "C" void kernel_launch(void* const* d_in, const int* in_sizes, int n_in,
                              void* d_out, int out_size, void* d_ws, size_t ws_size,
                              hipStream_t stream) {
    const float* x      = (const float*)d_in[0];
    const float* norm_w = (const float*)d_in[1];
    const float* norm_b = (const float*)d_in[2];
    const float* lin_w  = (const float*)d_in[3];
    const float* lin_b  = (const float*)d_in[4];
    float* out = (float*)d_out;
    __bf16* Bt = (__bf16*)d_ws;   // 512*1024*2 = 1 MiB

    prep_b_kernel<<<(NDIM * KDIM) / 256, 256, 0, stream>>>(lin_w, Bt);
    fused_ln_gemm_kernel<<<M_ROWS / BM, 256, 0, stream>>>(x, norm_w, norm_b, Bt, lin_b, out);
}